// Round 2
// baseline (223.060 us; speedup 1.0000x reference)
//
#include <hip/hip_runtime.h>
#include <hip/hip_cooperative_groups.h>

namespace cg = cooperative_groups;

#define BB 4
#define NN 1024
#define KK 9
#define C  32
#define CM 128
#define M  (BB*NN)       // 4096 rows
#define EPSB 1e-5f
#define SLOPE 0.01f

#define KPAD 296              // padded row stride (f16) for comp_w / kmat tiles
#define CHUNK_F16 (32*KPAD)   // 9472 f16 per (b,s) comp_w tile (32 n-rows)
#define CHUNK_F4  (CHUNK_F16/8) // 1184 float4 per tile

typedef _Float16 f16x8 __attribute__((ext_vector_type(8)));
typedef float    f32x4 __attribute__((ext_vector_type(4)));

__device__ __forceinline__ float leaky(float x){ return x > 0.f ? x : SLOPE*x; }

__device__ __forceinline__ float fexp2(float x){
#if __has_builtin(__builtin_amdgcn_exp2f)
  return __builtin_amdgcn_exp2f(x);
#else
  return exp2f(x);
#endif
}

// ---------------------------------------------------------------------------
// Single cooperative kernel, grid 256 x 512 (1 block/CU, co-resident).
// Phase 1: comp_w tiles -> cwh (128 active blocks, one (b,s) tile each).
// Phase 2: flash MFMA over all 1024 n; block bid owns output rows
//          bid*16..bid*16+15 (since (bid>>6)*1024+(bid&63)*16 == bid*16).
//          Emits zv in registers + BN stats.
// Phase 3: y = bn(z)+weights (yl in LDS), h = leaky(y@w1+b1) in hreg[4],
//          h-stats atomics.
// Phase 4: out = y + bn1(h)@w2 + b2.
// z/y/h NEVER touch global memory; only cwh + stats(320 floats) in ws.
// ---------------------------------------------------------------------------
__global__ __launch_bounds__(512, 2) void fused_all(
    const float* __restrict__ pos,
    const float* __restrict__ wts,
    const float* __restrict__ kpos,
    const float* __restrict__ conv_w,
    const float* __restrict__ bn_g,
    const float* __restrict__ bn_b,
    const float* __restrict__ w1,
    const float* __restrict__ b1,
    const float* __restrict__ bn1_g,
    const float* __restrict__ bn1_b,
    const float* __restrict__ w2,
    const float* __restrict__ b2,
    float* __restrict__ out,
    _Float16* __restrict__ cwh,
    float* __restrict__ stats)
{
  // union region: P1 conv_w (36 KB) | P2 cwt+kmt+pnl (65,024 B) |
  //               P3 w1l (16 KB)    | P4 w2l (16 KB) + hl (8 KB)
  __shared__ __align__(16) char smA[65024];
  __shared__ float yl[512];          // persistent phase 3 -> 4
  __shared__ float lt1[CM], lt2[CM];

  cg::grid_group grid = cg::this_grid();
  int bid = blockIdx.x;
  int tid = threadIdx.x;

  //================ Phase 1: comp_w ================
  if (bid < 128){
    float* cwl = (float*)smA;                    // 9x32x32 floats = 36 KB
    const float4* cs = (const float4*)conv_w;
    float4* cd = (float4*)cwl;
    for (int v = tid; v < (KK*C*C)/4; v += 512) cd[v] = cs[v];
    if (bid == 0){ for (int i = tid; i < 320; i += 512) stats[i] = 0.f; }
    int nl = tid & 31, dq = tid >> 5;            // dq 0..15 -> d = 2dq, 2dq+1
    int row = bid*32 + nl;
    float wreg[32];
    const float4* wr = (const float4*)(wts + (size_t)row*C);
    #pragma unroll
    for (int j = 0; j < 8; ++j){
      float4 t = wr[j];
      wreg[4*j]=t.x; wreg[4*j+1]=t.y; wreg[4*j+2]=t.z; wreg[4*j+3]=t.w;
    }
    __syncthreads();
    _Float16* outb = cwh + (size_t)bid*CHUNK_F16;
    #pragma unroll
    for (int k = 0; k < KK; ++k){
      float a0 = 0.f, a1 = 0.f;
      #pragma unroll
      for (int c = 0; c < C; ++c){
        float2 t = *(const float2*)&cwl[k*C*C + c*C + dq*2];  // LDS broadcast
        a0 += wreg[c]*t.x; a1 += wreg[c]*t.y;
      }
      outb[(dq*2+0)*KPAD + k*32 + nl] = (_Float16)a0;
      outb[(dq*2+1)*KPAD + k*32 + nl] = (_Float16)a1;
    }
  }
  grid.sync();

  //================ Phase 2: main MFMA ================
  _Float16 (*cwt)[32*KPAD] = (_Float16(*)[32*KPAD])smA;         // 2x18944 B
  _Float16 (*kmt)[16*KPAD] = (_Float16(*)[16*KPAD])(smA + 37888); // 2x9472 B
  float* pnl = (float*)(smA + 56832);                            // 8192 B
  float* red  = (float*)smA;           // epilogue overlay: 8x256 floats
  float* red2 = (float*)(smA + 18944); // epilogue overlay: 32x17 floats

  int b = bid >> 6, it = bid & 63;
  int lane = tid & 63, wid = tid >> 6;
  int mm = lane & 15, quad = lane >> 4;
  int c0 = (wid & 1) * 16, q = wid >> 1;
  int ig = tid >> 5, nl = tid & 31;

  const float BETA = -0.72134752f;  // -0.5 * log2(e)
  float Ak[KK], Bk[KK], Ck[KK];
  #pragma unroll
  for (int k = 0; k < KK; ++k){
    float kxx = kpos[2*k], kyy = kpos[2*k+1];
    Ak[k] = -2.f*BETA*kxx;
    Bk[k] = -2.f*BETA*kyy;
    Ck[k] = BETA*(kxx*kxx + kyy*kyy);
  }

#define STAGE(dstbuf, ss) do{ \
    const float4* s4_ = (const float4*)(cwh + (size_t)(b*32 + (ss))*CHUNK_F16); \
    _Pragma("unroll") \
    for (int rr_ = 0; rr_ < 3; ++rr_){ \
      int v_ = tid + rr_*512; \
      if (v_ < CHUNK_F4) \
        __builtin_amdgcn_global_load_lds( \
          (const __attribute__((address_space(1))) unsigned int*)(s4_ + v_), \
          (__attribute__((address_space(3))) unsigned int*)((dstbuf) + (size_t)(rr_*512 + wid*64)*8), \
          16, 0, 0); \
    } \
  }while(0)

#define GEN(dstbuf, ss) do{ \
    float dx_ = pix - pnl[2*((ss)*32 + nl)]; \
    float dy_ = piy - pnl[2*((ss)*32 + nl) + 1]; \
    float e0_ = BETA*(dx_*dx_ + dy_*dy_); \
    _Float16* kr_ = (dstbuf) + ig*KPAD + nl; \
    _Pragma("unroll") \
    for (int k = 0; k < KK; ++k){ \
      float t_ = (e0_ + Ck[k]) + dx_*Ak[k] + dy_*Bk[k]; \
      kr_[k*32] = (_Float16)fexp2(t_); \
    } \
  }while(0)

  ((float4*)pnl)[tid] = ((const float4*)(pos + (size_t)b*NN*2))[tid];
  STAGE(cwt[0], 0);
  __syncthreads();
  float pix = pnl[2*(it*16 + ig)];
  float piy = pnl[2*(it*16 + ig) + 1];
  GEN(kmt[0], 0);
  __syncthreads();

  f32x4 acc = {0.f,0.f,0.f,0.f};
  for (int s = 0; s < 32; ++s){
    int cur = s & 1, nxt = cur ^ 1;
    if (s < 31) STAGE(cwt[nxt], s+1);
    #pragma unroll
    for (int t = 0; t < 3; ++t){
      int ks = q + t*4;
      if (ks < KK){                      // wave-uniform
        f16x8 a  = *(const f16x8*)&kmt[cur][mm*KPAD + ks*32 + quad*8];
        f16x8 bf = *(const f16x8*)&cwt[cur][(c0+mm)*KPAD + ks*32 + quad*8];
        acc = __builtin_amdgcn_mfma_f32_16x16x32_f16(a, bf, acc, 0, 0, 0);
      }
    }
    if (s < 31) GEN(kmt[nxt], s+1);
    __syncthreads();
  }
#undef STAGE
#undef GEN

  // cross-wave reduce of k-subset partials; zv stays in a register
  float* rp = red + wid*256;
  #pragma unroll
  for (int r = 0; r < 4; ++r) rp[(quad*4 + r)*16 + mm] = acc[r];
  __syncthreads();
  float zv;
  {
    int r = tid >> 5, c = tid & 31;
    int half = c >> 4, cc = c & 15;
    int o = r*16 + cc;
    float v = red[half*256 + o] + red[(2+half)*256 + o]
            + red[(4+half)*256 + o] + red[(6+half)*256 + o];
    zv = leaky(v);
    red2[c*17 + r] = zv;
  }
  __syncthreads();
  if (tid < C){
    float s1 = 0.f, s2 = 0.f;
    #pragma unroll
    for (int r = 0; r < 16; ++r){ float t = red2[tid*17 + r]; s1 += t; s2 += t*t; }
    atomicAdd(&stats[tid], s1);
    atomicAdd(&stats[C + tid], s2);
  }
  grid.sync();

  //================ Phase 3: y = bn(z)+w ; h = leaky(y@w1+b1) ================
  int row0 = bid * 16;
  float* w1l = (float*)smA;   // 16 KB
  for (int i = tid; i < C*CM; i += 512) w1l[i] = w1[i];
  if (tid < CM){ lt1[tid] = 0.f; lt2[tid] = 0.f; }
  {
    int c = tid & 31, rl = tid >> 5;
    float s1 = stats[c], s2 = stats[C + c];
    float mean = s1 * (1.f/M);
    float var  = s2 * (1.f/M) - mean*mean;
    float sc = bn_g[c] * rsqrtf(var + EPSB);
    float sh = bn_b[c] - mean*sc;
    yl[tid] = zv*sc + sh + wts[(size_t)(row0 + rl)*C + c];  // coalesced
  }
  __syncthreads();
  float hreg[4];
  {
    int col = tid & 127;
    #pragma unroll
    for (int j = 0; j < 4; ++j){
      int e = tid + j*512;
      int rl = e >> 7;
      float acc1 = b1[col];
      #pragma unroll
      for (int c = 0; c < C; ++c) acc1 += yl[rl*C + c] * w1l[c*CM + col];
      acc1 = leaky(acc1);
      hreg[j] = acc1;
      atomicAdd(&lt1[col], acc1);
      atomicAdd(&lt2[col], acc1*acc1);
    }
  }
  __syncthreads();
  if (tid < CM){
    atomicAdd(&stats[2*C + tid],      lt1[tid]);
    atomicAdd(&stats[2*C + CM + tid], lt2[tid]);
  }
  grid.sync();

  //================ Phase 4: out = y + bn1(h)@w2 + b2 ================
  float* w2l = (float*)smA;             // 16 KB
  float* hl  = (float*)(smA + 16384);   // 8 KB
  for (int i = tid; i < CM*C; i += 512) w2l[i] = w2[i];
  {
    int col = tid & 127;
    float t1 = stats[2*C + col], t2 = stats[2*C + CM + col];
    float mean = t1*(1.f/M);
    float var  = t2*(1.f/M) - mean*mean;
    float sc = bn1_g[col]*rsqrtf(var + EPSB);
    float sh = bn1_b[col] - mean*sc;
    #pragma unroll
    for (int j = 0; j < 4; ++j){
      hl[tid + j*512] = hreg[j]*sc + sh;
    }
  }
  __syncthreads();
  {
    int c = tid & 31, rl = tid >> 5;
    float acc2 = b2[c];
    #pragma unroll
    for (int jj = 0; jj < CM; ++jj) acc2 += hl[rl*CM + jj] * w2l[jj*C + c];
    out[(size_t)(row0 + rl)*C + c] = yl[tid] + acc2;  // coalesced
  }
}

// ---------------------------------------------------------------------------
extern "C" void kernel_launch(void* const* d_in, const int* in_sizes, int n_in,
                              void* d_out, int out_size, void* d_ws, size_t ws_size,
                              hipStream_t stream) {
  const float* positions = (const float*)d_in[0];
  const float* weights   = (const float*)d_in[1];
  const float* kpos      = (const float*)d_in[2];
  const float* conv_w    = (const float*)d_in[3];
  const float* bn_g      = (const float*)d_in[4];
  const float* bn_b      = (const float*)d_in[5];
  const float* w1        = (const float*)d_in[6];
  const float* b1        = (const float*)d_in[7];
  const float* bn1_g     = (const float*)d_in[8];
  const float* bn1_b     = (const float*)d_in[9];
  const float* w2        = (const float*)d_in[10];
  const float* b2        = (const float*)d_in[11];
  float* out = (float*)d_out;

  float* ws = (float*)d_ws;
  _Float16* cwh = (_Float16*)ws;                       // 128 tiles
  float* stats  = ws + (size_t)128*CHUNK_F16/2;        // 320 floats

  void* args[] = {
    (void*)&positions, (void*)&weights, (void*)&kpos, (void*)&conv_w,
    (void*)&bn_g, (void*)&bn_b, (void*)&w1, (void*)&b1,
    (void*)&bn1_g, (void*)&bn1_b, (void*)&w2, (void*)&b2,
    (void*)&out, (void*)&cwh, (void*)&stats
  };
  hipLaunchCooperativeKernel((void*)fused_all, dim3(256), dim3(512),
                             args, 0, stream);
}

// Round 3
// 139.187 us; speedup vs baseline: 1.6026x; 1.6026x over previous
//
#include <hip/hip_runtime.h>

#define BB 4
#define NN 1024
#define KK 9
#define C  32
#define CM 128
#define M  (BB*NN)       // 4096 rows
#define EPSB 1e-5f
#define SLOPE 0.01f

#define KPAD 296              // padded row stride (f16) for comp_w / kmat tiles
#define CHUNK_F16 (32*KPAD)   // 9472 f16 per (b,s) comp_w tile (32 n-rows)
#define CHUNK_F4  (CHUNK_F16/8) // 1184 float4 per tile

typedef _Float16 f16x8 __attribute__((ext_vector_type(8)));
typedef _Float16 f16x4 __attribute__((ext_vector_type(4)));
typedef float    f32x4 __attribute__((ext_vector_type(4)));

__device__ __forceinline__ float leaky(float x){ return x > 0.f ? x : SLOPE*x; }

__device__ __forceinline__ float fexp2(float x){
#if __has_builtin(__builtin_amdgcn_exp2f)
  return __builtin_amdgcn_exp2f(x);
#else
  return exp2f(x);
#endif
}

// ---------------------------------------------------------------------------
// K1: comp_w tiles cwh[(b*32+s)*CHUNK_F16 ...] (f16, row stride KPAD)
//      tile layout [c][k*32+nl] = sum_c' w[row][c'] * conv_w[k][c'][c],
//      row = (b*32+s)*32+nl
// grid 384 = (b,s) x kt(3 k's each); thread = (nl 32) x (dq 8: 4 d each)
// Block 0 also zeroes the stats buffer.
// ---------------------------------------------------------------------------
__global__ __launch_bounds__(256) void k1_compw(const float* __restrict__ w,
                                                const float* __restrict__ conv_w,
                                                _Float16* __restrict__ cwh,
                                                float* __restrict__ stats){
  __shared__ float cwl[3*C*C];   // 12 KB: conv_w k-slice
  int bid = blockIdx.x;
  int kt  = bid % 3;
  int s   = (bid/3) & 31, b = bid/96;
  int tid = threadIdx.x;
  if (bid == 0){ for (int i = tid; i < 320; i += 256) stats[i] = 0.f; }

  const float4* cs = (const float4*)(conv_w + kt*3*C*C);
  float4* cd = (float4*)cwl;
  for (int v = tid; v < 768; v += 256) cd[v] = cs[v];

  int nl = tid & 31, dq = tid >> 5;
  int row = (b*32 + s)*32 + nl;
  float wreg[32];
  const float4* wr = (const float4*)(w + (size_t)row*C);
  #pragma unroll
  for (int j = 0; j < 8; ++j){
    float4 t = wr[j];
    wreg[4*j]=t.x; wreg[4*j+1]=t.y; wreg[4*j+2]=t.z; wreg[4*j+3]=t.w;
  }
  __syncthreads();

  _Float16* outb = cwh + (size_t)(b*32 + s)*CHUNK_F16;
  const float4* cv = (const float4*)cwl;
  #pragma unroll
  for (int kl = 0; kl < 3; ++kl){
    float a0=0.f, a1=0.f, a2=0.f, a3=0.f;
    #pragma unroll
    for (int c = 0; c < C; ++c){
      float4 t = cv[kl*256 + c*8 + dq];   // conv_w[kt*3+kl][c][dq*4..+3], broadcast
      a0 += wreg[c]*t.x; a1 += wreg[c]*t.y; a2 += wreg[c]*t.z; a3 += wreg[c]*t.w;
    }
    int k = kt*3 + kl;
    outb[(dq*4+0)*KPAD + k*32 + nl] = (_Float16)a0;
    outb[(dq*4+1)*KPAD + k*32 + nl] = (_Float16)a1;
    outb[(dq*4+2)*KPAD + k*32 + nl] = (_Float16)a2;
    outb[(dq*4+3)*KPAD + k*32 + nl] = (_Float16)a3;
  }
}

// ---------------------------------------------------------------------------
// K2: flash MFMA, grid 256 (b,it), 512 thr (8 waves).
// T4 pipeline: 3-deep circular cwt staging via global_load_lds, counted
// vmcnt(4) (conservative: per-wave loads/tile in {2,3}; vmcnt retires in
// issue order, so <=4 outstanding with 2 newer tiles in flight guarantees
// the oldest tile landed).  Raw s_barrier + lgkmcnt(0) only — never
// vmcnt(0) in the main loop.  Dummy tail stages keep counts uniform.
// Writes z = leaky(sum) + BN stats.
// ---------------------------------------------------------------------------
__global__ __launch_bounds__(512) void k2_main(const float* __restrict__ pos,
                                               const float* __restrict__ kpos,
                                               const _Float16* __restrict__ cwh,
                                               float* __restrict__ z,
                                               float* __restrict__ stats){
  __shared__ __align__(16) _Float16 cwt[3][32*KPAD];  // 56832 B (3-deep)
  __shared__ __align__(16) _Float16 kmt[2][16*KPAD];  // 18944 B (double-buffered)
  __shared__ __align__(16) float pnl[NN*2];           // 8192 B
  // epilogue scratch overlays cwt (dead after the loop + vmcnt(0) drain):
  float* red  = (float*)&cwt[0][0];   // 8*256 floats
  float* red2 = (float*)&cwt[1][0];   // 32*17 floats

  int bid = blockIdx.x;
  int b = bid >> 6, it = bid & 63;
  int tid = threadIdx.x;
  int lane = tid & 63, wid = tid >> 6;
  int mm = lane & 15, quad = lane >> 4;
  int c0 = (wid & 1) * 16, q = wid >> 1;
  // GEN role: gk = wave-pair k-group, ig = row, np = n-quad (vector writes)
  int gk = tid >> 7, ig = (tid >> 3) & 15, np = tid & 7;

  const float BETA = -0.72134752f;  // -0.5 * log2(e)
  float Ak[KK], Bk[KK], Ck[KK];
  #pragma unroll
  for (int k = 0; k < KK; ++k){
    float kxx = kpos[2*k], kyy = kpos[2*k+1];
    Ak[k] = -2.f*BETA*kxx;
    Bk[k] = -2.f*BETA*kyy;
    Ck[k] = BETA*(kxx*kxx + kyy*kyy);
  }

#define STAGE(dstbuf, ss) do{ \
    const float4* s4_ = (const float4*)(cwh + (size_t)(b*32 + (ss))*CHUNK_F16); \
    _Pragma("unroll") \
    for (int rr_ = 0; rr_ < 3; ++rr_){ \
      int v_ = tid + rr_*512; \
      if (v_ < CHUNK_F4) \
        __builtin_amdgcn_global_load_lds( \
          (const __attribute__((address_space(1))) unsigned int*)(s4_ + v_), \
          (__attribute__((address_space(3))) unsigned int*)((dstbuf) + (size_t)(rr_*512 + wid*64)*8), \
          16, 0, 0); \
    } \
  }while(0)

  // kmat gen: thread (gk,ig,np) computes 4 n for k in {gk, gk+4, gk+8<9},
  // vectorized f16x4 LDS writes.
#define GEN(dstbuf, ss) do{ \
    float dx_[4], dy_[4], e0_[4]; \
    _Pragma("unroll") \
    for (int jj = 0; jj < 4; ++jj){ \
      int nl_ = np*4 + jj; \
      dx_[jj] = pix - pnl[2*((ss)*32 + nl_)]; \
      dy_[jj] = piy - pnl[2*((ss)*32 + nl_) + 1]; \
      e0_[jj] = BETA*(dx_[jj]*dx_[jj] + dy_[jj]*dy_[jj]); \
    } \
    _Pragma("unroll") \
    for (int t_ = 0; t_ < 3; ++t_){ \
      int k_ = gk + t_*4; \
      if (k_ < KK){ \
        f16x4 ev_; \
        _Pragma("unroll") \
        for (int jj = 0; jj < 4; ++jj){ \
          float x_ = (e0_[jj] + Ck[k_]) + dx_[jj]*Ak[k_] + dy_[jj]*Bk[k_]; \
          ev_[jj] = (_Float16)fexp2(x_); \
        } \
        *(f16x4*)&(dstbuf)[ig*KPAD + k_*32 + np*4] = ev_; \
      } \
    } \
  }while(0)

  // prologue: positions + tiles 0,1; full drain once is fine here
  ((float4*)pnl)[tid] = ((const float4*)(pos + (size_t)b*NN*2))[tid];
  STAGE(cwt[0], 0);
  STAGE(cwt[1], 1);
  __syncthreads();
  float pix = pnl[2*(it*16 + ig)];
  float piy = pnl[2*(it*16 + ig) + 1];
  GEN(kmt[0], 0);
  asm volatile("s_waitcnt lgkmcnt(0)" ::: "memory");
  __builtin_amdgcn_s_barrier();
  __builtin_amdgcn_sched_barrier(0);

  f32x4 acc = {0.f,0.f,0.f,0.f};
  for (int s = 0; s < 32; ++s){
    int cur = s & 1;
    int ss = (s+2 > 31) ? 31 : s+2;     // dummy tail stages keep vmcnt uniform
    STAGE(cwt[(s+2)%3], ss);
    if (s < 31) GEN(kmt[cur^1], s+1);   // overlaps the in-flight loads
    asm volatile("s_waitcnt vmcnt(4)" ::: "memory");   // tile s landed
    __builtin_amdgcn_sched_barrier(0);
    const _Float16* cwb = cwt[s % 3];
    #pragma unroll
    for (int t = 0; t < 3; ++t){
      int ks = q + t*4;
      if (ks < KK){                      // wave-uniform
        f16x8 a  = *(const f16x8*)&kmt[cur][mm*KPAD + ks*32 + quad*8];
        f16x8 bf = *(const f16x8*)&cwb[(c0+mm)*KPAD + ks*32 + quad*8];
        acc = __builtin_amdgcn_mfma_f32_16x16x32_f16(a, bf, acc, 0, 0, 0);
      }
    }
    asm volatile("s_waitcnt lgkmcnt(0)" ::: "memory");  // GEN writes visible,
    __builtin_amdgcn_sched_barrier(0);                  // own ds_reads retired
    __builtin_amdgcn_s_barrier();
    __builtin_amdgcn_sched_barrier(0);
  }
#undef STAGE
#undef GEN
  // drain dummy tail loads before overlaying cwt with epilogue scratch
  asm volatile("s_waitcnt vmcnt(0)" ::: "memory");
  __builtin_amdgcn_s_barrier();
  __builtin_amdgcn_sched_barrier(0);

  // cross-wave reduce of the 4 k-subset partials per c-half
  float* rp = red + wid*256;
  #pragma unroll
  for (int r = 0; r < 4; ++r) rp[(quad*4 + r)*16 + mm] = acc[r];
  __syncthreads();
  {
    int r = tid >> 5, c = tid & 31;
    int half = c >> 4, cc = c & 15;
    int o = r*16 + cc;
    float v = red[half*256 + o] + red[(2+half)*256 + o]
            + red[(4+half)*256 + o] + red[(6+half)*256 + o];
    v = leaky(v);
    z[((size_t)b*NN + it*16 + r)*C + c] = v;   // 512 consecutive floats
    red2[c*17 + r] = v;
  }
  __syncthreads();
  if (tid < C){
    float s1 = 0.f, s2 = 0.f;
    #pragma unroll
    for (int r = 0; r < 16; ++r){ float t = red2[tid*17 + r]; s1 += t; s2 += t*t; }
    atomicAdd(&stats[tid], s1);
    atomicAdd(&stats[C + tid], s2);
  }
}

// ---------------------------------------------------------------------------
// K4: y = bn(z)+weights ; h = leaky(y@w1+b1) ; stats for h (stats[64..319])
// 8 rows/block, grid 512 -> 2 blocks/CU for latency hiding.
// ---------------------------------------------------------------------------
__global__ __launch_bounds__(256) void k4_mlp1(const float* __restrict__ z,
                                               const float* __restrict__ weights,
                                               const float* __restrict__ bn_g,
                                               const float* __restrict__ bn_b,
                                               const float* __restrict__ w1,
                                               const float* __restrict__ b1,
                                               float* __restrict__ stats,
                                               float* __restrict__ y,
                                               float* __restrict__ h){
  __shared__ float w1l[C*CM];   // 16 KB
  __shared__ float yl[8*C];
  __shared__ float lt1[CM], lt2[CM];
  int tid = threadIdx.x;
  int row0 = blockIdx.x * 8;
  for (int i = tid; i < C*CM; i += 256) w1l[i] = w1[i];
  if (tid < CM){ lt1[tid]=0.f; lt2[tid]=0.f; }
  {
    int c  = tid & (C-1);
    int rl = tid >> 5;
    float s1 = stats[c], s2 = stats[C + c];
    float mean = s1 * (1.f/M);
    float var  = s2 * (1.f/M) - mean*mean;
    float sc = bn_g[c] * rsqrtf(var + EPSB);
    float sh = bn_b[c] - mean*sc;
    int row = row0 + rl;
    float v = z[(size_t)row*C + c]*sc + sh + weights[(size_t)row*C + c];
    yl[tid] = v;
    y[(size_t)row*C + c] = v;
  }
  __syncthreads();
  {
    int col = tid & (CM-1);   // constant across j
    float la1 = 0.f, la2 = 0.f;
    #pragma unroll
    for (int j = 0; j < 4; ++j){
      int e = tid + j*256;
      int rl  = e >> 7;
      float acc = b1[col];
      #pragma unroll
      for (int c = 0; c < C; ++c) acc += yl[rl*C + c] * w1l[c*CM + col];
      acc = leaky(acc);
      h[(size_t)(row0+rl)*CM + col] = acc;
      la1 += acc; la2 += acc*acc;
    }
    atomicAdd(&lt1[col], la1);
    atomicAdd(&lt2[col], la2);
  }
  __syncthreads();
  if (tid < CM){
    atomicAdd(&stats[2*C + tid],      lt1[tid]);
    atomicAdd(&stats[2*C + CM + tid], lt2[tid]);
  }
}

// ---------------------------------------------------------------------------
// K5: out = y + (bn1(h) @ w2 + b2).  8 rows/block, grid 512.
// ---------------------------------------------------------------------------
__global__ __launch_bounds__(256) void k5_mlp2(const float* __restrict__ h,
                                               const float* __restrict__ y,
                                               const float* __restrict__ bn1_g,
                                               const float* __restrict__ bn1_b,
                                               const float* __restrict__ w2,
                                               const float* __restrict__ b2,
                                               const float* __restrict__ stats,
                                               float* __restrict__ out){
  __shared__ float w2l[CM*C];   // 16 KB
  __shared__ float hl[8*CM];    // 4 KB
  int tid = threadIdx.x;
  int row0 = blockIdx.x * 8;
  for (int i = tid; i < CM*C; i += 256) w2l[i] = w2[i];
  {
    int col = tid & (CM-1);
    float t1 = stats[2*C + col], t2 = stats[2*C + CM + col];
    float mean = t1*(1.f/M);
    float var  = t2*(1.f/M) - mean*mean;
    float sc = bn1_g[col]*rsqrtf(var + EPSB);
    float sh = bn1_b[col] - mean*sc;
    #pragma unroll
    for (int j = 0; j < 4; ++j){
      int e = tid + j*256;
      int rl  = e >> 7;
      hl[e] = h[(size_t)(row0+rl)*CM + col]*sc + sh;
    }
  }
  __syncthreads();
  {
    int c  = tid & (C-1);
    int rl = tid >> 5;
    float acc = b2[c];
    #pragma unroll
    for (int jj = 0; jj < CM; ++jj) acc += hl[rl*CM + jj] * w2l[jj*C + c];
    int row = row0 + rl;
    out[(size_t)row*C + c] = y[(size_t)row*C + c] + acc;
  }
}

// ---------------------------------------------------------------------------
extern "C" void kernel_launch(void* const* d_in, const int* in_sizes, int n_in,
                              void* d_out, int out_size, void* d_ws, size_t ws_size,
                              hipStream_t stream) {
  const float* positions = (const float*)d_in[0];
  const float* weights   = (const float*)d_in[1];
  const float* kpos      = (const float*)d_in[2];
  const float* conv_w    = (const float*)d_in[3];
  const float* bn_g      = (const float*)d_in[4];
  const float* bn_b      = (const float*)d_in[5];
  const float* w1        = (const float*)d_in[6];
  const float* b1        = (const float*)d_in[7];
  const float* bn1_g     = (const float*)d_in[8];
  const float* bn1_b     = (const float*)d_in[9];
  const float* w2        = (const float*)d_in[10];
  const float* b2        = (const float*)d_in[11];
  float* out = (float*)d_out;

  float* ws = (float*)d_ws;
  size_t off = 0;
  _Float16* cwh = (_Float16*)(ws + off); off += (size_t)128*CHUNK_F16/2;
  float* z     = ws + off; off += (size_t)M*C;
  float* y     = ws + off; off += (size_t)M*C;
  float* h     = ws + off; off += (size_t)M*CM;
  float* stats = ws + off; off += 320;

  k1_compw<<<384, 256, 0, stream>>>(weights, conv_w, cwh, stats);
  k2_main <<<256, 512, 0, stream>>>(positions, kpos, cwh, z, stats);
  k4_mlp1 <<<M/8, 256, 0, stream>>>(z, weights, bn_g, bn_b, w1, b1, stats, y, h);
  k5_mlp2 <<<M/8, 256, 0, stream>>>(h, y, bn1_g, bn1_b, w2, b2, stats, out);
}

// Round 4
// 129.541 us; speedup vs baseline: 1.7219x; 1.0745x over previous
//
#include <hip/hip_runtime.h>

#define BB 4
#define NN 1024
#define KK 9
#define C  32
#define CM 128
#define M  (BB*NN)       // 4096 rows
#define EPSB 1e-5f
#define SLOPE 0.01f

#define KPAD 296         // kmt row stride (f16): 288 + 8 (2-way banks, 16B aligned)
#define WTS  40          // wT row stride (f16): 32 + 8 (16B aligned, 2-way banks)
#define GST  296         // g_lds row stride (f32) = 74 float4
#define CWS  288         // cwT row stride (f32) = 72 float4 (XOR-swizzled blocks)

typedef _Float16 f16x8 __attribute__((ext_vector_type(8)));
typedef _Float16 f16x4 __attribute__((ext_vector_type(4)));
typedef float    f32x4 __attribute__((ext_vector_type(4)));

__device__ __forceinline__ float leaky(float x){ return x > 0.f ? x : SLOPE*x; }

__device__ __forceinline__ float fexp2(float x){
#if __has_builtin(__builtin_amdgcn_exp2f)
  return __builtin_amdgcn_exp2f(x);
#else
  return exp2f(x);
#endif
}

// ---------------------------------------------------------------------------
// K2: reordered einsum.  g[i,k,c'] = sum_n km[i,n,k] * w[n,c']  (MFMA, f16 in,
// f32 acc, per-k accumulators), then per-block epilogue
// y[i,c] = sum_{k,c'} g[i,k,c'] * conv_w[k,c',c]  (VALU f32, LDS).
// Eliminates K1 + the comp_w global tensor (155 MB of L2 re-reads -> 33 MB).
// Grid 256 = (b, it); 512 thr (8 waves: half=wid&1 -> c'-half, q=wid>>1 ->
// k subset {q, q+4, q+8<9}).  Double-buffered wT/kmt, reg-staged w chunk
// (1 float2/thread), raw s_barrier + lgkmcnt(0) only (vmem never drained
// in-loop; compiler inserts the counted wait for the reg prefetch).
// Writes z = leaky(y), per-block z-stats to zpart (no atomics), and block 0
// zeroes stats[0..256) for K4's h-stat atomics.
// ---------------------------------------------------------------------------
__global__ __launch_bounds__(512) void k2_main(const float* __restrict__ pos,
                                               const float* __restrict__ wts,
                                               const float* __restrict__ kpos,
                                               const float* __restrict__ conv_w,
                                               float* __restrict__ z,
                                               float* __restrict__ zpart,
                                               float* __restrict__ stats){
  __shared__ __align__(16) char smem[57984];
  _Float16* wT0 = (_Float16*)smem;              // [2][32*WTS] f16: 5120 B
  float*    pnl = (float*)(smem + 5120);        // 2048 f32: 8192 B -> 13312
  _Float16* km0 = (_Float16*)(smem + 13312);    // [2][16*KPAD] f16: 18944 -> 32256
  // epilogue overlays (all main-loop buffers dead after final loop barrier):
  float* gld  = (float*)smem;                   // [16][GST] f32: 18944
  float* cwT  = (float*)(smem + 18944);         // [32][CWS] f32 swz: 36864 -> 55808
  float* red2 = (float*)(smem + 55808);         // 544 f32 -> 57984 (disjoint)

  int bid = blockIdx.x;
  int b = bid >> 6, it = bid & 63;
  int tid = threadIdx.x;
  int lane = tid & 63, wid = tid >> 6;
  int mm = lane & 15, quad = lane >> 4;
  int c0 = (wid & 1) * 16, q = wid >> 1;
  int gk = tid >> 7, ig = (tid >> 3) & 15, np = tid & 7;  // GEN role
  int wn = tid >> 4, wc = (tid & 15) * 2;                 // wT-write role

  if (bid == 0){ for (int i = tid; i < 256; i += 512) stats[i] = 0.f; }

  const float BETA = -0.72134752f;  // -0.5 * log2(e)
  float Ak[KK], Bk[KK], Ck[KK];
  #pragma unroll
  for (int k = 0; k < KK; ++k){
    float kxx = kpos[2*k], kyy = kpos[2*k+1];
    Ak[k] = -2.f*BETA*kxx;
    Bk[k] = -2.f*BETA*kyy;
    Ck[k] = BETA*(kxx*kxx + kyy*kyy);
  }

  // w chunks of this batch: chunk j = 1024 consecutive floats (32n x 32c')
  const float2* wch = (const float2*)(wts + (size_t)b*NN*C);

#define WWRITE(dst, L) do{ \
    (dst)[wc*WTS + wn]     = (_Float16)(L).x; \
    (dst)[(wc+1)*WTS + wn] = (_Float16)(L).y; \
  }while(0)

#define GEN(dst, ss) do{ \
    float dx_[4], dy_[4], e0_[4]; \
    _Pragma("unroll") \
    for (int jj = 0; jj < 4; ++jj){ \
      int nl_ = np*4 + jj; \
      dx_[jj] = pix - pnl[2*((ss)*32 + nl_)]; \
      dy_[jj] = piy - pnl[2*((ss)*32 + nl_) + 1]; \
      e0_[jj] = BETA*(dx_[jj]*dx_[jj] + dy_[jj]*dy_[jj]); \
    } \
    _Pragma("unroll") \
    for (int t_ = 0; t_ < 3; ++t_){ \
      int k_ = gk + t_*4; \
      if (k_ < KK){ \
        f16x4 ev_; \
        _Pragma("unroll") \
        for (int jj = 0; jj < 4; ++jj){ \
          float x_ = (e0_[jj] + Ck[k_]) + dx_[jj]*Ak[k_] + dy_[jj]*Bk[k_]; \
          ev_[jj] = (_Float16)fexp2(x_); \
        } \
        *(f16x4*)&(dst)[ig*KPAD + k_*32 + np*4] = ev_; \
      } \
    } \
  }while(0)

  // prologue: positions + chunk0 -> wT[0], prefetch chunk1
  ((float4*)pnl)[tid] = ((const float4*)(pos + (size_t)b*NN*2))[tid];
  float2 L0 = wch[tid];           // chunk 0
  float2 Ln = wch[512 + tid];     // chunk 1 (stays in flight)
  WWRITE(wT0, L0);
  __syncthreads();
  float pix = pnl[2*(it*16 + ig)];
  float piy = pnl[2*(it*16 + ig) + 1];
  GEN(km0, 0);
  asm volatile("s_waitcnt lgkmcnt(0)" ::: "memory");
  __builtin_amdgcn_s_barrier();
  __builtin_amdgcn_sched_barrier(0);

  f32x4 acc0 = {0.f,0.f,0.f,0.f}, acc1 = {0.f,0.f,0.f,0.f}, acc2 = {0.f,0.f,0.f,0.f};
  for (int s = 0; s < 32; ++s){
    int cur = s & 1;
    if (s < 31){
      float2 Lw = Ln;                              // chunk s+1
      if (s < 30) Ln = wch[(size_t)(s+2)*512 + tid];
      _Float16* wTn = wT0 + (cur^1)*(32*WTS);
      WWRITE(wTn, Lw);                             // compiler-counted vmcnt wait
      _Float16* kmn = km0 + (cur^1)*(16*KPAD);
      GEN(kmn, s+1);
    }
    // MFMA on current buffers (written last iter, barrier'd)
    const _Float16* kmc = km0 + cur*(16*KPAD);
    const _Float16* wTc = wT0 + cur*(32*WTS);
    f16x8 bf = *(const f16x8*)&wTc[(c0+mm)*WTS + quad*8];
    f16x8 a0 = *(const f16x8*)&kmc[mm*KPAD + (q+0)*32 + quad*8];
    acc0 = __builtin_amdgcn_mfma_f32_16x16x32_f16(a0, bf, acc0, 0, 0, 0);
    f16x8 a1 = *(const f16x8*)&kmc[mm*KPAD + (q+4)*32 + quad*8];
    acc1 = __builtin_amdgcn_mfma_f32_16x16x32_f16(a1, bf, acc1, 0, 0, 0);
    if (q == 0){                                   // k=8, wave-uniform
      f16x8 a2 = *(const f16x8*)&kmc[mm*KPAD + 8*32 + quad*8];
      acc2 = __builtin_amdgcn_mfma_f32_16x16x32_f16(a2, bf, acc2, 0, 0, 0);
    }
    asm volatile("s_waitcnt lgkmcnt(0)" ::: "memory");
    __builtin_amdgcn_sched_barrier(0);
    __builtin_amdgcn_s_barrier();
    __builtin_amdgcn_sched_barrier(0);
  }
#undef WWRITE
#undef GEN

  // ---- epilogue: g -> LDS, conv_w -> LDS (swizzled), contract on VALU ----
  #pragma unroll
  for (int r = 0; r < 4; ++r){
    gld[(quad*4+r)*GST + (q+0)*32 + c0+mm] = acc0[r];
    gld[(quad*4+r)*GST + (q+4)*32 + c0+mm] = acc1[r];
  }
  if (q == 0){
    #pragma unroll
    for (int r = 0; r < 4; ++r)
      gld[(quad*4+r)*GST + 8*32 + c0+mm] = acc2[r];
  }
  // stage conv_w[k][c'][c] -> cwT[c][ (k*32+c') blocks XOR-swizzled by c&7 ]
  for (int v = tid; v < (KK*C*C)/4; v += 512){   // 2304 float4, coalesced
    float4 cv = ((const float4*)conv_w)[v];
    int f = v*4;
    int kc = f >> 5;                 // k*32 + c'
    int cb = f & 31;                 // 4 consecutive c
    int q4 = kc >> 2, sub = kc & 3;
    #pragma unroll
    for (int j = 0; j < 4; ++j){
      int c = cb + j;
      cwT[c*CWS + ((q4 ^ (c & 7))<<2) + sub] = (&cv.x)[j];
    }
  }
  __syncthreads();

  int rr = tid >> 5, cc = tid & 31;
  const float4* g4 = (const float4*)&gld[rr*GST];
  const float4* w4 = (const float4*)&cwT[cc*CWS];
  int sw = cc & 7;
  f32x4 ya = {0.f,0.f,0.f,0.f}, yb = {0.f,0.f,0.f,0.f};
  for (int k = 0; k < KK; ++k){
    #pragma unroll
    for (int c4 = 0; c4 < 8; c4 += 2){
      float4 gv = g4[k*8 + c4];
      float4 wv = w4[(k*8 + c4) ^ sw];
      ya[0] += gv.x*wv.x; ya[1] += gv.y*wv.y; ya[2] += gv.z*wv.z; ya[3] += gv.w*wv.w;
      float4 gv2 = g4[k*8 + c4 + 1];
      float4 wv2 = w4[(k*8 + c4 + 1) ^ sw];
      yb[0] += gv2.x*wv2.x; yb[1] += gv2.y*wv2.y; yb[2] += gv2.z*wv2.z; yb[3] += gv2.w*wv2.w;
    }
  }
  float yv = (ya[0]+ya[1]) + (ya[2]+ya[3]) + (yb[0]+yb[1]) + (yb[2]+yb[3]);
  yv = leaky(yv);
  z[((size_t)b*NN + it*16 + rr)*C + cc] = yv;    // 512 consecutive floats
  red2[cc*17 + rr] = yv;
  __syncthreads();
  if (tid < C){
    float s1 = 0.f, s2 = 0.f;
    #pragma unroll
    for (int r = 0; r < 16; ++r){ float t = red2[tid*17 + r]; s1 += t; s2 += t*t; }
    zpart[tid*256 + bid]            = s1;        // [0][c][bid]
    zpart[32*256 + tid*256 + bid]   = s2;        // [1][c][bid]
  }
}

// ---------------------------------------------------------------------------
// K4: zpart reduce -> z-BN; y = bn(z)+weights ; h = leaky(y@w1+b1);
// h-stats atomics into stats[0..255] (zeroed by K2).  8 rows/block, grid 512.
// ---------------------------------------------------------------------------
__global__ __launch_bounds__(256) void k4_mlp1(const float* __restrict__ z,
                                               const float* __restrict__ weights,
                                               const float* __restrict__ bn_g,
                                               const float* __restrict__ bn_b,
                                               const float* __restrict__ w1,
                                               const float* __restrict__ b1,
                                               const float* __restrict__ zpart,
                                               float* __restrict__ stats,
                                               float* __restrict__ y,
                                               float* __restrict__ h){
  __shared__ float w1l[C*CM];   // 16 KB
  __shared__ float yl[8*C];
  __shared__ float lt1[CM], lt2[CM];
  __shared__ float zs[2][8][32];
  __shared__ float zf[2][32];
  int tid = threadIdx.x;
  int row0 = blockIdx.x * 8;
  for (int v = tid; v < C*CM/4; v += 256)
    ((float4*)w1l)[v] = ((const float4*)w1)[v];
  if (tid < CM){ lt1[tid]=0.f; lt2[tid]=0.f; }
  {
    int c = tid & 31, seg = tid >> 5;
    const float4* p1 = (const float4*)&zpart[c*256 + seg*32];
    const float4* p2 = (const float4*)&zpart[8192 + c*256 + seg*32];
    float s1 = 0.f, s2 = 0.f;
    #pragma unroll
    for (int j = 0; j < 8; ++j){
      float4 a = p1[j]; s1 += (a.x+a.y)+(a.z+a.w);
      float4 d = p2[j]; s2 += (d.x+d.y)+(d.z+d.w);
    }
    zs[0][seg][c] = s1; zs[1][seg][c] = s2;
  }
  __syncthreads();
  if (tid < 64){
    int st = tid >> 5, c = tid & 31;
    float s = 0.f;
    #pragma unroll
    for (int g = 0; g < 8; ++g) s += zs[st][g][c];
    zf[st][c] = s;
  }
  __syncthreads();
  {
    int c  = tid & (C-1);
    int rl = tid >> 5;
    float mean = zf[0][c] * (1.f/M);
    float var  = zf[1][c] * (1.f/M) - mean*mean;
    float sc = bn_g[c] * rsqrtf(var + EPSB);
    float sh = bn_b[c] - mean*sc;
    int row = row0 + rl;
    float v = z[(size_t)row*C + c]*sc + sh + weights[(size_t)row*C + c];
    yl[tid] = v;
    y[(size_t)row*C + c] = v;
  }
  __syncthreads();
  {
    int col = tid & (CM-1);
    float la1 = 0.f, la2 = 0.f;
    #pragma unroll
    for (int j = 0; j < 4; ++j){
      int e = tid + j*256;
      int rl  = e >> 7;
      float acc = b1[col];
      #pragma unroll
      for (int c = 0; c < C; ++c) acc += yl[rl*C + c] * w1l[c*CM + col];
      acc = leaky(acc);
      h[(size_t)(row0+rl)*CM + col] = acc;
      la1 += acc; la2 += acc*acc;
    }
    atomicAdd(&lt1[col], la1);
    atomicAdd(&lt2[col], la2);
  }
  __syncthreads();
  if (tid < CM){
    atomicAdd(&stats[tid],      lt1[tid]);
    atomicAdd(&stats[CM + tid], lt2[tid]);
  }
}

// ---------------------------------------------------------------------------
// K5: out = y + (bn1(h) @ w2 + b2).  8 rows/block, grid 512.
// ---------------------------------------------------------------------------
__global__ __launch_bounds__(256) void k5_mlp2(const float* __restrict__ h,
                                               const float* __restrict__ y,
                                               const float* __restrict__ bn1_g,
                                               const float* __restrict__ bn1_b,
                                               const float* __restrict__ w2,
                                               const float* __restrict__ b2,
                                               const float* __restrict__ stats,
                                               float* __restrict__ out){
  __shared__ float w2l[CM*C];   // 16 KB
  __shared__ float hl[8*CM];    // 4 KB
  int tid = threadIdx.x;
  int row0 = blockIdx.x * 8;
  for (int v = tid; v < CM*C/4; v += 256)
    ((float4*)w2l)[v] = ((const float4*)w2)[v];
  {
    int col = tid & (CM-1);
    float t1 = stats[col], t2 = stats[CM + col];
    float mean = t1*(1.f/M);
    float var  = t2*(1.f/M) - mean*mean;
    float sc = bn1_g[col]*rsqrtf(var + EPSB);
    float sh = bn1_b[col] - mean*sc;
    #pragma unroll
    for (int j = 0; j < 4; ++j){
      int e = tid + j*256;
      int rl  = e >> 7;
      hl[e] = h[(size_t)(row0+rl)*CM + col]*sc + sh;
    }
  }
  __syncthreads();
  {
    int c  = tid & (C-1);
    int rl = tid >> 5;
    float acc = b2[c];
    #pragma unroll
    for (int jj = 0; jj < CM; ++jj) acc += hl[rl*CM + jj] * w2l[jj*C + c];
    int row = row0 + rl;
    out[(size_t)row*C + c] = y[(size_t)row*C + c] + acc;
  }
}

// ---------------------------------------------------------------------------
extern "C" void kernel_launch(void* const* d_in, const int* in_sizes, int n_in,
                              void* d_out, int out_size, void* d_ws, size_t ws_size,
                              hipStream_t stream) {
  const float* positions = (const float*)d_in[0];
  const float* weights   = (const float*)d_in[1];
  const float* kpos      = (const float*)d_in[2];
  const float* conv_w    = (const float*)d_in[3];
  const float* bn_g      = (const float*)d_in[4];
  const float* bn_b      = (const float*)d_in[5];
  const float* w1        = (const float*)d_in[6];
  const float* b1        = (const float*)d_in[7];
  const float* bn1_g     = (const float*)d_in[8];
  const float* bn1_b     = (const float*)d_in[9];
  const float* w2        = (const float*)d_in[10];
  const float* b2        = (const float*)d_in[11];
  float* out = (float*)d_out;

  float* ws = (float*)d_ws;
  float* z     = ws;                    // M*C      = 131072
  float* y     = ws + 131072;           // M*C      = 131072
  float* h     = ws + 262144;           // M*CM     = 524288
  float* zpart = ws + 786432;           // 2*32*256 = 16384
  float* stats = ws + 802816;           // 256

  k2_main<<<256, 512, 0, stream>>>(positions, weights, kpos, conv_w, z, zpart, stats);
  k4_mlp1<<<M/8, 256, 0, stream>>>(z, weights, bn_g, bn_b, w1, b1, zpart, stats, y, h);
  k5_mlp2<<<M/8, 256, 0, stream>>>(h, y, bn1_g, bn1_b, w2, b2, stats, out);
}

// Round 5
// 124.194 us; speedup vs baseline: 1.7961x; 1.0431x over previous
//
#include <hip/hip_runtime.h>

#define BB 4
#define NN 1024
#define KK 9
#define C  32
#define CM 128
#define M  (BB*NN)       // 4096 rows
#define EPSB 1e-5f
#define SLOPE 0.01f

#define KPAD 296         // kmt row stride (f16): 288 + 8 (16B aligned)
#define WTS  40          // wT row stride (f16): 32 + 8 (16B aligned)
#define GAP  296         // gA / cwB row stride (f16), 592 B = 37*16 ✓
#define HPAD 136         // K5 hA/w2B row stride (f16), 272 B = 17*16 ✓

typedef _Float16 f16x8 __attribute__((ext_vector_type(8)));
typedef _Float16 f16x4 __attribute__((ext_vector_type(4)));
typedef float    f32x4 __attribute__((ext_vector_type(4)));

__device__ __forceinline__ float leaky(float x){ return x > 0.f ? x : SLOPE*x; }

__device__ __forceinline__ float fexp2(float x){
#if __has_builtin(__builtin_amdgcn_exp2f)
  return __builtin_amdgcn_exp2f(x);
#else
  return exp2f(x);
#endif
}

// ---------------------------------------------------------------------------
// K2: g[i,k,c'] = sum_n km[i,n,k]*w[n,c'] (MFMA main loop, unchanged from R4),
// then epilogue y = g @ conv_w as a SECOND MFMA (hi/lo f16 split, ~f32-exact)
// instead of the old 144-b128-reads/thread VALU contraction.
// Grid 256 = (b, it); 512 thr (8 waves: c'-half = wid&1, q = wid>>1 ->
// k subset {q, q+4, q+8<9}).
// ---------------------------------------------------------------------------
__global__ __launch_bounds__(512) void k2_main(const float* __restrict__ pos,
                                               const float* __restrict__ wts,
                                               const float* __restrict__ kpos,
                                               const float* __restrict__ conv_w,
                                               float* __restrict__ z,
                                               float* __restrict__ zpart,
                                               float* __restrict__ stats){
  __shared__ __align__(16) char smem[67200];
  // main loop layout:
  _Float16* wT0 = (_Float16*)smem;              // [2][32*WTS] f16: 5120 B
  float*    pnl = (float*)(smem + 5120);        // 2048 f32: 8192 B -> 13312
  _Float16* km0 = (_Float16*)(smem + 13312);    // [2][16*KPAD]: 18944 -> 32256
  // epilogue overlays (main-loop buffers dead after final loop barrier):
  _Float16* gAh = (_Float16*)smem;              // [16][GAP] 9472
  _Float16* gAl = (_Float16*)(smem + 9472);     // 9472  -> 18944
  _Float16* cwBh = (_Float16*)(smem + 18944);   // [32][GAP] 18944 -> 37888
  _Float16* cwBl = (_Float16*)(smem + 37888);   // 18944 -> 56832
  float* red  = (float*)(smem + 56832);         // 8*256 f32 -> 65024
  float* red2 = (float*)(smem + 65024);         // 544 f32 -> 67200

  int bid = blockIdx.x;
  int b = bid >> 6, it = bid & 63;
  int tid = threadIdx.x;
  int lane = tid & 63, wid = tid >> 6;
  int mm = lane & 15, quad = lane >> 4;
  int c0 = (wid & 1) * 16, q = wid >> 1;
  int gk = tid >> 7, ig = (tid >> 3) & 15, np = tid & 7;  // GEN role
  int wn = tid >> 4, wc = (tid & 15) * 2;                 // wT-write role

  if (bid == 0){ for (int i = tid; i < 256; i += 512) stats[i] = 0.f; }

  const float BETA = -0.72134752f;  // -0.5 * log2(e)
  float Ak[KK], Bk[KK], Ck[KK];
  #pragma unroll
  for (int k = 0; k < KK; ++k){
    float kxx = kpos[2*k], kyy = kpos[2*k+1];
    Ak[k] = -2.f*BETA*kxx;
    Bk[k] = -2.f*BETA*kyy;
    Ck[k] = BETA*(kxx*kxx + kyy*kyy);
  }

  const float2* wch = (const float2*)(wts + (size_t)b*NN*C);

#define WWRITE(dst, L) do{ \
    (dst)[wc*WTS + wn]     = (_Float16)(L).x; \
    (dst)[(wc+1)*WTS + wn] = (_Float16)(L).y; \
  }while(0)

#define GEN(dst, ss) do{ \
    float dx_[4], dy_[4], e0_[4]; \
    _Pragma("unroll") \
    for (int jj = 0; jj < 4; ++jj){ \
      int nl_ = np*4 + jj; \
      dx_[jj] = pix - pnl[2*((ss)*32 + nl_)]; \
      dy_[jj] = piy - pnl[2*((ss)*32 + nl_) + 1]; \
      e0_[jj] = BETA*(dx_[jj]*dx_[jj] + dy_[jj]*dy_[jj]); \
    } \
    _Pragma("unroll") \
    for (int t_ = 0; t_ < 3; ++t_){ \
      int k_ = gk + t_*4; \
      if (k_ < KK){ \
        f16x4 ev_; \
        _Pragma("unroll") \
        for (int jj = 0; jj < 4; ++jj){ \
          float x_ = (e0_[jj] + Ck[k_]) + dx_[jj]*Ak[k_] + dy_[jj]*Bk[k_]; \
          ev_[jj] = (_Float16)fexp2(x_); \
        } \
        *(f16x4*)&(dst)[ig*KPAD + k_*32 + np*4] = ev_; \
      } \
    } \
  }while(0)

  // prologue: positions + chunk0 -> wT[0], prefetch chunk1
  ((float4*)pnl)[tid] = ((const float4*)(pos + (size_t)b*NN*2))[tid];
  float2 L0 = wch[tid];           // chunk 0
  float2 Ln = wch[512 + tid];     // chunk 1 (stays in flight)
  WWRITE(wT0, L0);
  __syncthreads();
  float pix = pnl[2*(it*16 + ig)];
  float piy = pnl[2*(it*16 + ig) + 1];
  GEN(km0, 0);
  asm volatile("s_waitcnt lgkmcnt(0)" ::: "memory");
  __builtin_amdgcn_s_barrier();
  __builtin_amdgcn_sched_barrier(0);

  f32x4 acc0 = {0.f,0.f,0.f,0.f}, acc1 = {0.f,0.f,0.f,0.f}, acc2 = {0.f,0.f,0.f,0.f};
  for (int s = 0; s < 32; ++s){
    int cur = s & 1;
    if (s < 31){
      float2 Lw = Ln;                              // chunk s+1
      if (s < 30) Ln = wch[(size_t)(s+2)*512 + tid];
      _Float16* wTn = wT0 + (cur^1)*(32*WTS);
      WWRITE(wTn, Lw);                             // compiler-counted vmcnt wait
      _Float16* kmn = km0 + (cur^1)*(16*KPAD);
      GEN(kmn, s+1);
    }
    const _Float16* kmc = km0 + cur*(16*KPAD);
    const _Float16* wTc = wT0 + cur*(32*WTS);
    f16x8 bf = *(const f16x8*)&wTc[(c0+mm)*WTS + quad*8];
    f16x8 a0 = *(const f16x8*)&kmc[mm*KPAD + (q+0)*32 + quad*8];
    acc0 = __builtin_amdgcn_mfma_f32_16x16x32_f16(a0, bf, acc0, 0, 0, 0);
    f16x8 a1 = *(const f16x8*)&kmc[mm*KPAD + (q+4)*32 + quad*8];
    acc1 = __builtin_amdgcn_mfma_f32_16x16x32_f16(a1, bf, acc1, 0, 0, 0);
    if (q == 0){                                   // k=8, wave-uniform
      f16x8 a2 = *(const f16x8*)&kmc[mm*KPAD + 8*32 + quad*8];
      acc2 = __builtin_amdgcn_mfma_f32_16x16x32_f16(a2, bf, acc2, 0, 0, 0);
    }
    asm volatile("s_waitcnt lgkmcnt(0)" ::: "memory");
    __builtin_amdgcn_sched_barrier(0);
    __builtin_amdgcn_s_barrier();
    __builtin_amdgcn_sched_barrier(0);
  }
#undef WWRITE
#undef GEN

  // ---- epilogue: y = g @ conv_w via hi/lo f16 MFMA ----
  // write g (acc regs, C-layout) -> gA hi/lo in A-fragment layout [i][k*32+c']
  #pragma unroll
  for (int r = 0; r < 4; ++r){
    int row = quad*4 + r;
    float v0 = acc0[r];
    _Float16 h0 = (_Float16)v0;
    gAh[row*GAP + (q+0)*32 + c0+mm] = h0;
    gAl[row*GAP + (q+0)*32 + c0+mm] = (_Float16)(v0 - (float)h0);
    float v1 = acc1[r];
    _Float16 h1 = (_Float16)v1;
    gAh[row*GAP + (q+4)*32 + c0+mm] = h1;
    gAl[row*GAP + (q+4)*32 + c0+mm] = (_Float16)(v1 - (float)h1);
    if (q == 0){
      float v2 = acc2[r];
      _Float16 h2 = (_Float16)v2;
      gAh[row*GAP + 8*32 + c0+mm] = h2;
      gAl[row*GAP + 8*32 + c0+mm] = (_Float16)(v2 - (float)h2);
    }
  }
  // stage conv_w[k][c'][c] -> cwB[c][k*32+c'] hi/lo (B-fragment layout)
  for (int v = tid; v < (KK*C*C)/4; v += 512){   // 2304 float4, coalesced
    float4 cv = ((const float4*)conv_w)[v];
    int f = v*4;
    int k  = f >> 10;
    int cp = (f >> 5) & 31;
    int cb = f & 31;
    #pragma unroll
    for (int j = 0; j < 4; ++j){
      float x = (&cv.x)[j];
      _Float16 hi = (_Float16)x;
      int c = cb + j;
      cwBh[c*GAP + k*32 + cp] = hi;
      cwBl[c*GAP + k*32 + cp] = (_Float16)(x - (float)hi);
    }
  }
  __syncthreads();

  // wave (c-half = wid&1, q): partial y tile over its k-slices
  f32x4 yacc = {0.f,0.f,0.f,0.f};
  #pragma unroll
  for (int t = 0; t < 3; ++t){
    int ks = q + t*4;
    if (ks < KK){                                  // wave-uniform
      f16x8 ah = *(const f16x8*)&gAh[mm*GAP + ks*32 + quad*8];
      f16x8 al = *(const f16x8*)&gAl[mm*GAP + ks*32 + quad*8];
      f16x8 bh = *(const f16x8*)&cwBh[(c0+mm)*GAP + ks*32 + quad*8];
      f16x8 bl = *(const f16x8*)&cwBl[(c0+mm)*GAP + ks*32 + quad*8];
      yacc = __builtin_amdgcn_mfma_f32_16x16x32_f16(ah, bh, yacc, 0, 0, 0);
      yacc = __builtin_amdgcn_mfma_f32_16x16x32_f16(al, bh, yacc, 0, 0, 0);
      yacc = __builtin_amdgcn_mfma_f32_16x16x32_f16(ah, bl, yacc, 0, 0, 0);
    }
  }
  #pragma unroll
  for (int r = 0; r < 4; ++r) red[wid*256 + (quad*4+r)*16 + mm] = yacc[r];
  __syncthreads();
  {
    int rr = tid >> 5, cc = tid & 31;
    int half = cc >> 4, c15 = cc & 15;
    int o = rr*16 + c15;
    float yv = red[(0+half)*256 + o] + red[(2+half)*256 + o]
             + red[(4+half)*256 + o] + red[(6+half)*256 + o];
    yv = leaky(yv);
    z[((size_t)b*NN + it*16 + rr)*C + cc] = yv;    // 512 consecutive floats
    red2[cc*17 + rr] = yv;
  }
  __syncthreads();
  if (tid < C){
    float s1 = 0.f, s2 = 0.f;
    #pragma unroll
    for (int r = 0; r < 16; ++r){ float t = red2[tid*17 + r]; s1 += t; s2 += t*t; }
    zpart[tid*256 + bid]          = s1;
    zpart[32*256 + tid*256 + bid] = s2;
  }
}

// ---------------------------------------------------------------------------
// K4: zpart reduce -> z-BN; y = bn(z)+weights ; h = leaky(y@w1+b1) via
// hi/lo f16 MFMA (K=32 -> 1 K-step/tile); h-stats atomics into stats[0..255].
// h passed to K5 as packed hi/lo f16x4 in MFMA-C order (coalesced b64).
// Grid 256 (16 rows/block), 256 thr (4 waves; wave -> col-tiles wid*2+{0,1}).
// ---------------------------------------------------------------------------
__global__ __launch_bounds__(256) void k4_mlp1(const float* __restrict__ z,
                                               const float* __restrict__ weights,
                                               const float* __restrict__ bn_g,
                                               const float* __restrict__ bn_b,
                                               const float* __restrict__ w1,
                                               const float* __restrict__ b1,
                                               const float* __restrict__ zpart,
                                               float* __restrict__ stats,
                                               float* __restrict__ y,
                                               _Float16* __restrict__ hhl){
  __shared__ __align__(16) _Float16 yAh[16*WTS], yAl[16*WTS];       // 1280 B each
  __shared__ __align__(16) _Float16 w1Bh[CM*WTS], w1Bl[CM*WTS];     // 10240 B each
  __shared__ float lt1[CM], lt2[CM], b1l[CM];
  __shared__ float zs[2][8][32];
  __shared__ float zf[2][32];
  int tid = threadIdx.x;
  int lane = tid & 63, wid = tid >> 6, mm = lane & 15, quad = lane >> 4;
  int row0 = blockIdx.x * 16;

  {
    int c = tid & 31, seg = tid >> 5;
    const float4* p1 = (const float4*)&zpart[c*256 + seg*32];
    const float4* p2 = (const float4*)&zpart[8192 + c*256 + seg*32];
    float s1 = 0.f, s2 = 0.f;
    #pragma unroll
    for (int j = 0; j < 8; ++j){
      float4 a = p1[j]; s1 += (a.x+a.y)+(a.z+a.w);
      float4 d = p2[j]; s2 += (d.x+d.y)+(d.z+d.w);
    }
    zs[0][seg][c] = s1; zs[1][seg][c] = s2;
  }
  if (tid < CM){ lt1[tid]=0.f; lt2[tid]=0.f; }
  if (tid >= 128) b1l[tid-128] = b1[tid-128];
  __syncthreads();
  if (tid < 64){
    int st = tid >> 5, c = tid & 31;
    float s = 0.f;
    #pragma unroll
    for (int g = 0; g < 8; ++g) s += zs[st][g][c];
    zf[st][c] = s;
  }
  __syncthreads();

  // y = bn(z) + weights; stage as hi/lo A-fragments
  #pragma unroll
  for (int e = tid; e < 512; e += 256){
    int c = e & 31, rl = e >> 5;
    float mean = zf[0][c] * (1.f/M);
    float var  = zf[1][c] * (1.f/M) - mean*mean;
    float sc = bn_g[c] * rsqrtf(var + EPSB);
    float sh = bn_b[c] - mean*sc;
    int row = row0 + rl;
    float v = z[(size_t)row*C + c]*sc + sh + weights[(size_t)row*C + c];
    y[(size_t)row*C + c] = v;
    _Float16 hi = (_Float16)v;
    yAh[rl*WTS + c] = hi;
    yAl[rl*WTS + c] = (_Float16)(v - (float)hi);
  }
  // stage w1[c][col] -> w1B[col][c] hi/lo (B-fragment layout)
  for (int v = tid; v < (C*CM)/4; v += 256){   // 1024 float4
    float4 t = ((const float4*)w1)[v];
    int c = v >> 5, col = (v & 31)*4;
    #pragma unroll
    for (int j = 0; j < 4; ++j){
      float x = (&t.x)[j];
      _Float16 hi = (_Float16)x;
      w1Bh[(col+j)*WTS + c] = hi;
      w1Bl[(col+j)*WTS + c] = (_Float16)(x - (float)hi);
    }
  }
  __syncthreads();

  f16x8 ah = *(const f16x8*)&yAh[mm*WTS + quad*8];
  f16x8 al = *(const f16x8*)&yAl[mm*WTS + quad*8];
  #pragma unroll
  for (int t2 = 0; t2 < 2; ++t2){
    int ct = wid*2 + t2;
    f16x8 bh = *(const f16x8*)&w1Bh[(ct*16+mm)*WTS + quad*8];
    f16x8 bl = *(const f16x8*)&w1Bl[(ct*16+mm)*WTS + quad*8];
    f32x4 acc = {0.f,0.f,0.f,0.f};
    acc = __builtin_amdgcn_mfma_f32_16x16x32_f16(ah, bh, acc, 0, 0, 0);
    acc = __builtin_amdgcn_mfma_f32_16x16x32_f16(al, bh, acc, 0, 0, 0);
    acc = __builtin_amdgcn_mfma_f32_16x16x32_f16(ah, bl, acc, 0, 0, 0);
    float bias = b1l[ct*16+mm];
    float la1 = 0.f, la2 = 0.f;
    f16x4 phi, plo;
    #pragma unroll
    for (int r = 0; r < 4; ++r){
      float v = leaky(acc[r] + bias);
      la1 += v; la2 += v*v;
      _Float16 hi = (_Float16)v;
      phi[r] = hi; plo[r] = (_Float16)(v - (float)hi);
    }
    atomicAdd(&lt1[ct*16+mm], la1);
    atomicAdd(&lt2[ct*16+mm], la2);
    size_t base = ((size_t)(blockIdx.x*256 + tid)*2 + t2)*4;
    *(f16x4*)&hhl[base] = phi;
    *(f16x4*)&hhl[(size_t)M*CM + base] = plo;
  }
  __syncthreads();
  if (tid < CM){
    atomicAdd(&stats[tid],      lt1[tid]);
    atomicAdd(&stats[CM + tid], lt2[tid]);
  }
}

// ---------------------------------------------------------------------------
// K5: out = y + bn1(h)@w2 + b2, with BN1 folded into w2:
//   (h*sc+sh)@w2 = h@(sc⊙w2) + (sh@w2);  bias' = b2 + sh@w2.
// h@w2' via hi/lo f16 MFMA (K=128 -> 4 K-steps, split 2 ways across waves).
// Grid 256 (16 rows/block), 256 thr (4 waves: ct = wid&1, kh = wid>>1).
// ---------------------------------------------------------------------------
__global__ __launch_bounds__(256) void k5_mlp2(const _Float16* __restrict__ hhl,
                                               const float* __restrict__ y,
                                               const float* __restrict__ bn1_g,
                                               const float* __restrict__ bn1_b,
                                               const float* __restrict__ w2,
                                               const float* __restrict__ b2,
                                               const float* __restrict__ stats,
                                               float* __restrict__ out){
  __shared__ __align__(16) _Float16 hAh[16*HPAD], hAl[16*HPAD];     // 4352 B each
  __shared__ __align__(16) _Float16 w2Bh[C*HPAD], w2Bl[C*HPAD];     // 8704 B each
  __shared__ float ssc[CM], ssh[CM];
  __shared__ float bl2[C];
  __shared__ float red[4*256];
  int tid = threadIdx.x;
  int lane = tid & 63, wid = tid >> 6, mm = lane & 15, quad = lane >> 4;
  int row0 = blockIdx.x * 16;

  // h load (mirror of K4's packed store order)
  size_t hb = ((size_t)(blockIdx.x*256 + tid)*2)*4;
  f16x4 h0 = *(const f16x4*)&hhl[hb];
  f16x4 h1 = *(const f16x4*)&hhl[hb + 4];
  f16x4 l0 = *(const f16x4*)&hhl[(size_t)M*CM + hb];
  f16x4 l1 = *(const f16x4*)&hhl[(size_t)M*CM + hb + 4];

  if (tid < CM){
    float t1 = stats[tid], t2 = stats[CM + tid];
    float mean = t1*(1.f/M);
    float var  = t2*(1.f/M) - mean*mean;
    float sc = bn1_g[tid]*rsqrtf(var + EPSB);
    ssc[tid] = sc;
    ssh[tid] = bn1_b[tid] - mean*sc;
  }
  if (tid >= 128 && tid < 160) bl2[tid-128] = b2[tid-128];

  // scatter h into A-fragment layout [row][j]
  #pragma unroll
  for (int t2 = 0; t2 < 2; ++t2){
    int col = (wid*2 + t2)*16 + mm;
    #pragma unroll
    for (int r = 0; r < 4; ++r){
      int row = quad*4 + r;
      hAh[row*HPAD + col] = t2 ? h1[r] : h0[r];
      hAl[row*HPAD + col] = t2 ? l1[r] : l0[r];
    }
  }
  __syncthreads();   // ssc/ssh/bl2 ready

  // stage w2' = sc⊙w2 hi/lo (B-layout [c][j]) + bias' partials
  for (int v = tid; v < (CM*C)/4; v += 256){   // 1024 float4
    float4 t = ((const float4*)w2)[v];
    int j = v >> 3, c4 = (v & 7)*4;
    float scj = ssc[j], shj = ssh[j];
    #pragma unroll
    for (int jj = 0; jj < 4; ++jj){
      float x = (&t.x)[jj];
      int c = c4 + jj;
      atomicAdd(&bl2[c], shj * x);
      float xp = x * scj;
      _Float16 hi = (_Float16)xp;
      w2Bh[c*HPAD + j] = hi;
      w2Bl[c*HPAD + j] = (_Float16)(xp - (float)hi);
    }
  }
  __syncthreads();

  // MFMA: wave (ct = wid&1, kh = wid>>1): K-steps ks = kh*2 + {0,1}
  int ct = wid & 1, kh = wid >> 1;
  f32x4 acc = {0.f,0.f,0.f,0.f};
  #pragma unroll
  for (int ks2 = 0; ks2 < 2; ++ks2){
    int ks = kh*2 + ks2;
    f16x8 ah = *(const f16x8*)&hAh[mm*HPAD + ks*32 + quad*8];
    f16x8 al = *(const f16x8*)&hAl[mm*HPAD + ks*32 + quad*8];
    f16x8 bh = *(const f16x8*)&w2Bh[(ct*16+mm)*HPAD + ks*32 + quad*8];
    f16x8 bl = *(const f16x8*)&w2Bl[(ct*16+mm)*HPAD + ks*32 + quad*8];
    acc = __builtin_amdgcn_mfma_f32_16x16x32_f16(ah, bh, acc, 0, 0, 0);
    acc = __builtin_amdgcn_mfma_f32_16x16x32_f16(al, bh, acc, 0, 0, 0);
    acc = __builtin_amdgcn_mfma_f32_16x16x32_f16(ah, bl, acc, 0, 0, 0);
  }
  #pragma unroll
  for (int r = 0; r < 4; ++r) red[wid*256 + (quad*4+r)*16 + mm] = acc[r];
  __syncthreads();

  #pragma unroll
  for (int e = tid; e < 512; e += 256){
    int rr = e >> 5, cc = e & 31;
    int half = cc >> 4;
    int o = rr*16 + (cc & 15);
    float val = red[half*256 + o] + red[(2+half)*256 + o];
    int row = row0 + rr;
    out[(size_t)row*C + cc] = y[(size_t)row*C + cc] + bl2[cc] + val;
  }
}

// ---------------------------------------------------------------------------
extern "C" void kernel_launch(void* const* d_in, const int* in_sizes, int n_in,
                              void* d_out, int out_size, void* d_ws, size_t ws_size,
                              hipStream_t stream) {
  const float* positions = (const float*)d_in[0];
  const float* weights   = (const float*)d_in[1];
  const float* kpos      = (const float*)d_in[2];
  const float* conv_w    = (const float*)d_in[3];
  const float* bn_g      = (const float*)d_in[4];
  const float* bn_b      = (const float*)d_in[5];
  const float* w1        = (const float*)d_in[6];
  const float* b1        = (const float*)d_in[7];
  const float* bn1_g     = (const float*)d_in[8];
  const float* bn1_b     = (const float*)d_in[9];
  const float* w2        = (const float*)d_in[10];
  const float* b2        = (const float*)d_in[11];
  float* out = (float*)d_out;

  float* ws = (float*)d_ws;
  float* z       = ws;                      // M*C = 131072
  float* y       = ws + 131072;             // M*C = 131072
  _Float16* hhl  = (_Float16*)(ws + 262144);// 2 * M*CM f16 = 524288 f32 slots
  float* zpart   = ws + 786432;             // 2*32*256 = 16384
  float* stats   = ws + 802816;             // 256

  k2_main<<<256, 512, 0, stream>>>(positions, weights, kpos, conv_w, z, zpart, stats);
  k4_mlp1<<<256, 256, 0, stream>>>(z, weights, bn_g, bn_b, w1, b1, zpart, stats, y, hhl);
  k5_mlp2<<<256, 256, 0, stream>>>(hhl, y, bn1_g, bn1_b, w2, b2, stats, out);
}